// Round 1
// 563.642 us; speedup vs baseline: 1.0550x; 1.0550x over previous
//
#include <hip/hip_runtime.h>
#include <hip/hip_bf16.h>

#define DEVI __device__ __forceinline__

typedef __attribute__((ext_vector_type(8))) short abf8;   // 8 x bf16 (4 VGPR)
typedef __attribute__((ext_vector_type(4))) float f32x4;  // MFMA acc

DEVI unsigned short f2bf(float f) {
  union { __hip_bfloat16 h; unsigned short u; } cvt;
  cvt.h = __float2bfloat16(f);
  return cvt.u;
}
DEVI float bf2f(unsigned short u) {
  return __uint_as_float(((unsigned)u) << 16);
}
DEVI void async16(const void* g, void* l) {
  // async global->LDS, 16B per lane; LDS dest = wave-uniform base + lane*16
  __builtin_amdgcn_global_load_lds((__attribute__((address_space(1))) void*)(g),
                                   (__attribute__((address_space(3))) void*)(l), 16, 0, 0);
}

// ---------------- K0w: fold pw into cv -> W3[dd][oc][ic] bf16, + pb3 ---------
// W3[dd][oc][ic] = sum_m cv_w[oc][m][dd] * pw_w[m][ic]   (bf16 MFMA, fp32 acc)
// pb3[oc][dd]    = sum_m cv_w[oc][m][dd] * pw_b[m]
__global__ __launch_bounds__(256) void k0w(const float* __restrict__ cv_w,
                                           const float* __restrict__ pw_w,
                                           const float* __restrict__ pw_b,
                                           unsigned short* __restrict__ cvb,
                                           float* __restrict__ pb3) {
  __shared__ __align__(16) unsigned short As[128 * 32];
  __shared__ __align__(16) unsigned short Bs[128 * 32];
  const int t = threadIdx.x;
  const int wv = t >> 6, ln = t & 63, q = ln >> 4, cl = ln & 15;
  const int dd = blockIdx.x;
  const int oc0 = blockIdx.y * 128, ic0 = blockIdx.z * 128;
  f32x4 acc[2][8] = {};
  float pacc = 0.0f;
  for (int m0 = 0; m0 < 256; m0 += 32) {
    __syncthreads();
    {  // stage A: As[ocr][mk] = bf16(cv_w[((oc0+ocr)*256 + m0+mk)*9 + dd])
      const int ocr = t >> 1, h = t & 1;
      const float* src = cv_w + ((size_t)(oc0 + ocr) * 256 + m0 + h * 16) * 9 + dd;
      unsigned short* dstp = As + ocr * 32 + h * 16;
      for (int j = 0; j < 16; ++j) dstp[j] = f2bf(src[j * 9]);
    }
    // stage B (transposed): Bs[icr][mk] = bf16(pw_w[(m0+mk)*256 + ic0+icr])
    for (int idx = t; idx < 4096; idx += 256) {
      int r = idx >> 7, c = idx & 127;
      Bs[c * 32 + r] = f2bf(pw_w[(size_t)(m0 + r) * 256 + ic0 + c]);
    }
    __syncthreads();
    if (blockIdx.z == 0 && t < 128) {  // pb3 partial for oc row t
      for (int mk = 0; mk < 32; ++mk) pacc += bf2f(As[t * 32 + mk]) * pw_b[m0 + mk];
    }
    abf8 a0 = *(const abf8*)(As + (wv * 32 + cl) * 32 + q * 8);
    abf8 a1 = *(const abf8*)(As + (wv * 32 + 16 + cl) * 32 + q * 8);
    for (int nt = 0; nt < 8; ++nt) {
      abf8 bf = *(const abf8*)(Bs + (nt * 16 + cl) * 32 + q * 8);
      acc[0][nt] = __builtin_amdgcn_mfma_f32_16x16x32_bf16(a0, bf, acc[0][nt], 0, 0, 0);
      acc[1][nt] = __builtin_amdgcn_mfma_f32_16x16x32_bf16(a1, bf, acc[1][nt], 0, 0, 0);
    }
  }
  if (blockIdx.z == 0 && t < 128) pb3[(size_t)(oc0 + t) * 9 + dd] = pacc;
  // C/D layout: col = cl, row = q*4 + reg
  for (int mt = 0; mt < 2; ++mt)
    for (int r = 0; r < 4; ++r)
      for (int nt = 0; nt < 8; ++nt) {
        int oc = oc0 + wv * 32 + mt * 16 + q * 4 + r;
        int ic = ic0 + nt * 16 + cl;
        cvb[((size_t)dd << 16) + oc * 256 + ic] = f2bf(acc[mt][nt][r]);
      }
}

// ---------------- K0q: effective bias per (u-class, v-class) -----------------
// bias9[(uc*3+vc)*256+oc] = cv_b[oc] + sum_{du in uc, dv in vc} pb3[oc][du*3+dv]
__global__ __launch_bounds__(256) void k0q(const float* __restrict__ pb3,
                                           const float* __restrict__ cv_b,
                                           float* __restrict__ bias9) {
  const int oc = threadIdx.x;
  float p[9];
  for (int i = 0; i < 9; ++i) p[i] = pb3[oc * 9 + i];
  const float cb = cv_b[oc];
  for (int uc = 0; uc < 3; ++uc)
    for (int vc = 0; vc < 3; ++vc) {
      int du0 = (uc == 0) ? 1 : 0, du1 = (uc == 2) ? 1 : 2;
      int dv0 = (vc == 0) ? 1 : 0, dv1 = (vc == 2) ? 1 : 2;
      float s = cb;
      for (int du = du0; du <= du1; ++du)
        for (int dv = dv0; dv <= dv1; ++dv) s += p[du * 3 + dv];
      bias9[(uc * 3 + vc) * 256 + oc] = s;
    }
}

// ---------------- K1a: Haar DWT + transpose -> t0[b][4c+k][u][v] bf16 --------
__global__ __launch_bounds__(256) void k1a_dwt(const float* __restrict__ x,
                                               unsigned short* __restrict__ t0) {
  __shared__ __align__(16) float L[64 * 65];
  const int t = threadIdx.x;
  const int u0 = (blockIdx.x & 3) * 32;
  const int v0 = (blockIdx.x >> 2) * 32;
  const int c = blockIdx.y, b = blockIdx.z;
  const float* xp = x + (((size_t)(b * 64 + c)) << 16);
  {
    const int row = t >> 2;
    const float* xr = xp + (size_t)(2 * v0 + row) * 256 + 2 * u0;
    float* Lr = L + row * 65;
    for (int j = 0; j < 4; ++j) {
      int col = ((t & 3) + j * 4) * 4;
      float4 val = *(const float4*)(xr + col);
      Lr[col] = val.x; Lr[col + 1] = val.y; Lr[col + 2] = val.z; Lr[col + 3] = val.w;
    }
  }
  __syncthreads();
  const int vv = t & 31;
  const int us = t >> 5;
  const size_t outc = ((size_t)(b * 256 + c * 4)) << 14;
  for (int pass = 0; pass < 4; ++pass) {
    int uu = us * 4 + pass;
    const float* Lp = L + (2 * vv) * 65 + 2 * uu;
    float a = Lp[0], bb = Lp[1], cc = Lp[65], dd = Lp[66];
    float sll = (a + bb + cc + dd) * 0.5f;
    float sch = (a + bb - cc - dd) * 0.5f;
    float scv = (a - bb + cc - dd) * 0.5f;
    float scd = (a - bb - cc + dd) * 0.5f;
    size_t base = outc + ((u0 + uu) << 7) + (v0 + vv);
    t0[base]         = f2bf(sll);
    t0[base + 16384] = f2bf(sch);
    t0[base + 32768] = f2bf(scv);
    t0[base + 49152] = f2bf(scd);
  }
}

// ---------------- K1b: depthwise 3x3 + bias -> t1 NHWC bf16 [b][u*128+v][ic] -
__global__ __launch_bounds__(256) void k1b_dw(const unsigned short* __restrict__ t0,
                                              const float* __restrict__ dww,
                                              const float* __restrict__ dwb,
                                              unsigned short* __restrict__ t1) {
  __shared__ __align__(16) unsigned short S[32 * 181];
  __shared__ __align__(16) unsigned short O[128 * 32];
  const int t = threadIdx.x;
  const int u0 = (blockIdx.x >> 3) * 8;
  const int v0 = (blockIdx.x & 7) * 16;
  const int icB = blockIdx.y * 32;
  const int b = blockIdx.z;
  const unsigned short* t0b = t0 + (((size_t)(b * 256 + icB)) << 14);
  for (int idx = t; idx < 5760; idx += 256) {
    int ic = idx / 180;
    int r = idx - ic * 180;
    int uu = r / 18;
    int vvq = r - uu * 18;
    int gu = u0 + uu - 1, gv = v0 + vvq - 1;
    unsigned short val = 0;
    if ((unsigned)gu < 128u && (unsigned)gv < 128u)
      val = t0b[((size_t)ic << 14) + (gu << 7) + gv];
    S[ic * 181 + r] = val;
  }
  __syncthreads();
  const int icp = t & 15, uu = (t >> 4) & 7, vh = t >> 7;
  const int cc0 = icB + icp * 2;
  float w0[9], w1[9];
  const float* wp = dww + cc0 * 9;
  for (int i = 0; i < 9; ++i) { w0[i] = wp[i]; w1[i] = wp[9 + i]; }
  const float b0 = dwb[cc0], b1 = dwb[cc0 + 1];
  const unsigned short* S0 = S + (icp * 2) * 181 + uu * 18 + vh * 8;
  const unsigned short* S1 = S0 + 181;
  float a0[3][3], a1[3][3];
  for (int du = 0; du < 3; ++du)
    for (int dv = 0; dv < 2; ++dv) {
      a0[du][dv] = bf2f(S0[du * 18 + dv]);
      a1[du][dv] = bf2f(S1[du * 18 + dv]);
    }
  unsigned* O32 = (unsigned*)O;
  for (int vv = 0; vv < 8; ++vv) {
    for (int du = 0; du < 3; ++du) {
      a0[du][2] = bf2f(S0[du * 18 + vv + 2]);
      a1[du][2] = bf2f(S1[du * 18 + vv + 2]);
    }
    float s0 = b0, s1 = b1;
    for (int du = 0; du < 3; ++du)
      for (int dv = 0; dv < 3; ++dv) {
        s0 += w0[du * 3 + dv] * a0[du][dv];
        s1 += w1[du * 3 + dv] * a1[du][dv];
      }
    int p = uu * 16 + vh * 8 + vv;
    O32[p * 16 + icp] = (unsigned)f2bf(s0) | ((unsigned)f2bf(s1) << 16);
    for (int du = 0; du < 3; ++du) {
      a0[du][0] = a0[du][1]; a0[du][1] = a0[du][2];
      a1[du][0] = a1[du][1]; a1[du][1] = a1[du][2];
    }
  }
  __syncthreads();
  const int p = t >> 1, hf = t & 1;
  const int pu = p >> 4, pv = p & 15;
  size_t gp = (size_t)((u0 + pu) * 128 + (v0 + pv));
  const uint4* src = (const uint4*)(O + p * 32 + hf * 16);
  uint4* dst = (uint4*)(t1 + ((((size_t)b * 16384) + gp) << 8) + icB + hf * 16);
  dst[0] = src[0];
  dst[1] = src[1];
}

// ---------------- K3: 3x3 conv (folded pw+cv), implicit GEMM + bias + GELU ---
// Per (du, ic0) round: stage 1 input u-row [130 v][32 ic] (rows 0/129 stay
// zero = v-halo) + 3 dv weight tiles; 48 MFMA per barrier pair.
// Swizzle: slot(seg,R) = (seg + (R>>1))&3 -> conflict-free b128 reads.
// Bias: position-dependent (zero-pad happens after pw_b in the reference),
// bias9[(uc*3+vc)*256+oc] selected by u-class (block-uniform) and v-class.
__global__ __launch_bounds__(256) void k3_cv(const unsigned short* __restrict__ t1,
                                             const unsigned short* __restrict__ cvb,
                                             const float* __restrict__ bias9,
                                             unsigned short* __restrict__ t3) {
  __shared__ __align__(16) char smem[34816];
  unsigned short* As = (unsigned short*)smem;             // 3 dv x [128 oc][32 ic] = 24576 B
  unsigned short* Bs = (unsigned short*)(smem + 24576);   // [130 v][32 ic] = 8320 B
  unsigned short* Ost = (unsigned short*)smem;            // [128 oc][136] (union)
  const int t = threadIdx.x;
  const int wv = t >> 6, ln = t & 63;
  const int oc0 = blockIdx.x * 128;
  const int u = blockIdx.y;
  const int b = blockIdx.z;
  const unsigned short* t1b = t1 + ((size_t)b << 22);
  const int q = ln >> 4, cl = ln & 15;
  const int lr = ln >> 2, sp = ln & 3;
  const int scA = (sp - (lr >> 1)) & 3;          // A: swizzle by row-in-chunk
  const int scB = (sp - ((1 + lr) >> 1)) & 3;    // B: physical row = 1+ch*16+lr
  const int soffA = ((q + (cl >> 1)) & 3) * 8;
  // zero halo rows 0 and 129 of Bs (never overwritten by staging)
  if (t < 32) ((unsigned*)Bs)[t < 16 ? t : (2064 + (t - 16))] = 0;
  f32x4 acc[2][8] = {};
  for (int du = 0; du < 3; ++du) {
    const int us = u + du - 1;
    if ((unsigned)us >= 128u) continue;          // uniform per block
    const unsigned short* trow = t1b + ((size_t)us << 15);
    const unsigned short* wdu = cvb + (((size_t)(du * 3)) << 16);
    for (int ic0 = 0; ic0 < 256; ic0 += 32) {
      __syncthreads();
      for (int g = wv; g < 32; g += 4) {
        if (g < 24) {                             // A: 3 dv x 8 chunks
          int dv = g >> 3, ch = g & 7;
          async16(wdu + (((size_t)dv) << 16) + (((size_t)(oc0 + ch * 16 + lr)) << 8) + ic0 + scA * 8,
                  As + dv * 4096 + ch * 512);
        } else {                                  // B: 8 chunks, phys rows 1..128
          int ch = g - 24;
          async16(trow + (((size_t)(ch * 16 + lr)) << 8) + ic0 + scB * 8,
                  Bs + 32 + ch * 512);
        }
      }
      __syncthreads();
      for (int dv = 0; dv < 3; ++dv) {
        const unsigned short* Adv = As + dv * 4096;
        abf8 a0 = *(const abf8*)(Adv + (wv * 32 + cl) * 32 + soffA);
        abf8 a1 = *(const abf8*)(Adv + (wv * 32 + 16 + cl) * 32 + soffA);
        const int slotB = ((q + ((cl + dv) >> 1)) & 3) * 8;
        const unsigned short* Bbase = Bs + (cl + dv) * 32 + slotB;
        for (int nt = 0; nt < 8; ++nt) {
          abf8 bf = *(const abf8*)(Bbase + nt * 512);
          acc[0][nt] = __builtin_amdgcn_mfma_f32_16x16x32_bf16(a0, bf, acc[0][nt], 0, 0, 0);
          acc[1][nt] = __builtin_amdgcn_mfma_f32_16x16x32_bf16(a1, bf, acc[1][nt], 0, 0, 0);
        }
      }
    }
  }
  __syncthreads();
  const int uc = (u == 0) ? 0 : ((u == 127) ? 2 : 1);
  const float* b9 = bias9 + uc * 3 * 256;
  const bool isv0 = (cl == 0), isv127 = (cl == 15);
  for (int mt = 0; mt < 2; ++mt) {
    int ocr = wv * 32 + mt * 16 + q * 4;
    for (int r = 0; r < 4; ++r) {
      int ocA = oc0 + ocr + r;
      float bmid = b9[256 + ocA - oc0 + oc0];     // vc=1
      float blo  = b9[ocA];                        // vc=0 (v==0)
      float bhi  = b9[512 + ocA];                  // vc=2 (v==127)
      bmid = b9[256 + ocA];
      for (int nt = 0; nt < 8; ++nt) {
        float bias = bmid;
        if (nt == 0 && isv0) bias = blo;
        else if (nt == 7 && isv127) bias = bhi;
        float xv = acc[mt][nt][r] + bias;
        float u_ = 0.7978845608028654f * xv * (1.0f + 0.044715f * xv * xv);
        float e = __expf(-2.0f * fabsf(u_));
        float th = (1.0f - e) / (1.0f + e);
        th = (u_ >= 0.0f) ? th : -th;
        float g = 0.5f * xv * (1.0f + th);
        Ost[(ocr + r) * 136 + nt * 16 + cl] = f2bf(g);
      }
    }
  }
  __syncthreads();
  const int rr = t >> 1, hf = t & 1;
  const uint4* src = (const uint4*)(Ost + rr * 136 + hf * 64);
  uint4* dst = (uint4*)(t3 + ((size_t)(b * 256 + oc0 + rr) << 14) + (u << 7) + hf * 64);
  for (int j = 0; j < 8; ++j) dst[j] = src[j];
}

// ---------------- K4: inverse transpose + IDWT -> out fp32 -------------------
__global__ __launch_bounds__(256) void k4_idwt(const unsigned short* __restrict__ t3,
                                               float* __restrict__ out) {
  __shared__ __align__(16) unsigned short L[4 * 32 * 34];
  const int t = threadIdx.x;
  const int w20 = (blockIdx.x & 3) * 32;
  const int h20 = (blockIdx.x >> 2) * 32;
  const int c = blockIdx.y, b = blockIdx.z;
  const unsigned short* t3b = t3 + (((size_t)(b * 256 + c * 4)) << 14);
  {
    const int row = t >> 1, hf = t & 1;
    const int k = row >> 5, w2i = row & 31;
    const unsigned* g = (const unsigned*)(t3b + ((size_t)k << 14) + ((w20 + w2i) << 7) + h20 + hf * 16);
    unsigned* l = (unsigned*)(L + (k * 32 + w2i) * 34 + hf * 16);
    for (int j = 0; j < 8; ++j) l[j] = g[j];
  }
  __syncthreads();
  const int w2 = t & 31;
  const int h2b = t >> 5;
  float* ob = out + (((size_t)(b * 64 + c)) << 16);
  for (int pass = 0; pass < 4; ++pass) {
    int h2 = h2b + pass * 8;
    int off = w2 * 34 + h2;
    float ll = bf2f(L[off]);
    float ch = bf2f(L[off + 1088]);
    float cv = bf2f(L[off + 2176]);
    float cd = bf2f(L[off + 3264]);
    float A  = (ll + ch + cv + cd) * 0.5f;
    float Bv = (ll + ch - cv - cd) * 0.5f;
    float Cv = (ll - ch + cv - cd) * 0.5f;
    float D  = (ll - ch - cv + cd) * 0.5f;
    int hg = (h20 + h2) * 2, wg = (w20 + w2) * 2;
    *(float2*)(ob + (size_t)hg * 256 + wg)       = make_float2(A, Bv);
    *(float2*)(ob + (size_t)(hg + 1) * 256 + wg) = make_float2(Cv, D);
  }
}

extern "C" void kernel_launch(void* const* d_in, const int* in_sizes, int n_in,
                              void* d_out, int out_size, void* d_ws, size_t ws_size,
                              hipStream_t stream) {
  const float* x    = (const float*)d_in[0];
  const float* dw_w = (const float*)d_in[1];
  const float* dw_b = (const float*)d_in[2];
  const float* pw_w = (const float*)d_in[3];
  const float* pw_b = (const float*)d_in[4];
  const float* cv_w = (const float*)d_in[5];
  const float* cv_b = (const float*)d_in[6];
  char* ws = (char*)d_ws;
  // ws layout: pb3 @0 (9216 B) | bias9 @16K (9216 B) | cvb(W3) @64K (1.18 MB)
  //            | bufA @2MiB (t0, then t3) | bufB @70MiB (t1). Total ~137 MiB.
  float* pb3           = (float*)ws;
  float* bias9         = (float*)(ws + 16384);
  unsigned short* cvb  = (unsigned short*)(ws + 65536);
  unsigned short* bufA = (unsigned short*)(ws + (size_t)(2u << 20));
  unsigned short* bufB = (unsigned short*)(ws + (size_t)(70u << 20));
  k0w<<<dim3(9, 2, 2), 256, 0, stream>>>(cv_w, pw_w, pw_b, cvb, pb3);
  k0q<<<1, 256, 0, stream>>>(pb3, cv_b, bias9);
  k1a_dwt<<<dim3(16, 64, 8), 256, 0, stream>>>(x, bufA);
  k1b_dw<<<dim3(128, 8, 8), 256, 0, stream>>>(bufA, dw_w, dw_b, bufB);
  k3_cv<<<dim3(2, 128, 8), 256, 0, stream>>>(bufB, cvb, bias9, bufA);
  k4_idwt<<<dim3(16, 64, 8), 256, 0, stream>>>(bufA, (float*)d_out);
}